// Round 12
// baseline (216.882 us; speedup 1.0000x reference)
//
#include <hip/hip_runtime.h>

// WaveNet inference on MFMA. Exploits: (1) only last timestep feeds the FC
// head, (2) skip overwritten each layer (only layer 15's matters),
// (3) receptive field at t=T-1 is 77 steps.
// Round 12 = R10 (best, 112us) + one surgical fix: phase3's C-preload
// (residual carry) comes from phase1's f32 acc registers (+shfl_xor(32) for
// the (r&3)==3 rows; single LDS read only for cross-wave row R+32) instead
// of 16 bank-conflicted scalar ds_read_b16. R9/R11 lesson kept: no extra
// serial work for barrier elimination — R10's 2-barrier layer structure.

#define BB 16
#define TT 8192
#define LL 16
#define W0 77
#define NT 256

typedef __attribute__((ext_vector_type(8)))  short short8;
typedef __attribute__((ext_vector_type(16))) float float16;

#define MFMA_B16(a, b, c) __builtin_amdgcn_mfma_f32_32x32x16_bf16(a, b, c, 0, 0, 0)

__device__ __forceinline__ short f2bs(float f) {   // f32 -> bf16 bits, RNE
  union { float ff; unsigned u; } v; v.ff = f;
  unsigned u = v.u;
  return (short)((u + 0x7FFFu + ((u >> 16) & 1u)) >> 16);
}
__device__ __forceinline__ float b2f(short h) {
  union { unsigned u; float f; } v;
  v.u = ((unsigned)(unsigned short)h) << 16; return v.f;
}
__device__ __forceinline__ float fast_sigmoid(float x) {
  return 1.f / (1.f + __expf(-x));
}
__device__ __forceinline__ float fast_tanh(float x) {
  return 2.f / (1.f + __expf(-2.f * x)) - 1.f;
}

// A-fragment halves from [row][32] bf16 LDS: A[m][k], k-local=(lane>>5)*8+j.
__device__ __forceinline__ void afrag2(const short* src, int row, int kh, short8* out) {
  out[0] = *(const short8*)&src[row * 32 + 8 * kh];
  out[1] = *(const short8*)&src[row * 32 + 16 + 8 * kh];
}

// chunk cid in [0,896): mat=cid>>7, h=(cid>>6)&1, ln=cid&63 -> n=ln&31,k2=ln>>5
// value j: W[16h+8k2+j][n] of matrix mat; dst offset = cid*8 shorts (b128).
__device__ __forceinline__ void load_chunk(
    int li, int cid, float* pf,
    const float* dil_w, const float* filt_w, const float* gate_w, const float* res_w)
{
  int mat = cid >> 7;
  int h = (cid >> 6) & 1, ln = cid & 63;
  int n = ln & 31, k2 = ln >> 5;
  int base = (li * 32 + n) * 32 + 16 * h + 8 * k2;
  if (mat == 6) {
    const float* p = res_w + base;
    #pragma unroll
    for (int j = 0; j < 8; j++) pf[j] = p[j];
  } else {
    const float* w = (mat < 2) ? dil_w : (mat < 4) ? filt_w : gate_w;
    const float* p = w + base * 2 + (mat & 1);
    #pragma unroll
    for (int j = 0; j < 8; j++) pf[j] = p[2 * j];
  }
}

__global__ __launch_bounds__(NT, 1) void wavenet_kernel(
    const int* __restrict__ tokens,
    const float* __restrict__ emb,
    const float* __restrict__ init_w, const float* __restrict__ init_b,
    const float* __restrict__ dil_w,  const float* __restrict__ dil_b,
    const float* __restrict__ filt_w, const float* __restrict__ filt_b,
    const float* __restrict__ gate_w, const float* __restrict__ gate_b,
    const float* __restrict__ res_w,  const float* __restrict__ res_b,
    const float* __restrict__ skip_w, const float* __restrict__ skip_b,
    const float* __restrict__ end1_w, const float* __restrict__ end1_b,
    const float* __restrict__ end2_w, const float* __restrict__ end2_b,
    const float* __restrict__ fc1_w,  const float* __restrict__ fc1_b,
    const float* __restrict__ fc2_w,  const float* __restrict__ fc2_b,
    const float* __restrict__ fc3_w,  const float* __restrict__ fc3_b,
    const float* __restrict__ fc4_w,  const float* __restrict__ fc4_b,
    float* __restrict__ out)
{
  __shared__ __align__(16) short bfw[2][7168];   // weight frags, double buffer
  __shared__ float bias2[2][128];
  __shared__ __align__(16) short xbuf[W0 * 32];
  __shared__ __align__(16) short pool[8624];     // emb stage (init) / rb+xm
  __shared__ int tok[W0];
  __shared__ float vecA[256], vecB[256];

  short* rb = pool;          // 76*32
  short* xm = pool + 2432;   // 76*32

  const int tid  = threadIdx.x;
  const int lane = tid & 63;
  const int wv   = tid >> 6;
  const int m    = lane & 31;
  const int kh   = lane >> 5;
  const int b    = blockIdx.x;

  // ---- tokens ----
  if (tid < W0) tok[tid] = tokens[b * TT + (TT - 1 - tid)];
  __syncthreads();

  // ---- stage emb rows (bf16, rows zero-padded to K=112) ----
  for (int cid = tid; cid < 77 * 14; cid += NT) {
    int u = cid / 14, s = cid % 14;
    const float* er = emb + tok[u] * 100 + s * 8;
    short8 v;
    if (s < 12) {
      #pragma unroll
      for (int j = 0; j < 8; j++) v[j] = f2bs(er[j]);
    } else if (s == 12) {
      #pragma unroll
      for (int j = 0; j < 4; j++) v[j] = f2bs(er[j]);
      #pragma unroll
      for (int j = 4; j < 8; j++) v[j] = 0;
    } else {
      #pragma unroll
      for (int j = 0; j < 8; j++) v[j] = 0;
    }
    *(short8*)&pool[u * 112 + s * 8] = v;
  }
  // stage layer-0 weight frags + biases directly (all threads)
  for (int cid = tid; cid < 896; cid += NT) {
    float pf[8];
    load_chunk(0, cid, pf, dil_w, filt_w, gate_w, res_w);
    short8 v;
    #pragma unroll
    for (int j = 0; j < 8; j++) v[j] = f2bs(pf[j]);
    *(short8*)&bfw[0][cid * 8] = v;
  }
  if (tid < 128) {
    const float* bsrc = (tid < 32) ? dil_b : (tid < 64) ? filt_b : (tid < 96) ? gate_b : res_b;
    bias2[0][tid] = bsrc[tid & 31];
  }
  __syncthreads();

  // ---- init conv (wave 0, MFMA over K=112) ----
  if (wv == 0) {
    short8 bi[7];
    #pragma unroll
    for (int s = 0; s < 7; s++) {
      const float* p = init_w + m * 100 + s * 16 + kh * 8;
      short8 v;
      if (s < 6) {
        #pragma unroll
        for (int j = 0; j < 8; j++) v[j] = f2bs(p[j]);
      } else if (kh == 0) {
        #pragma unroll
        for (int j = 0; j < 4; j++) v[j] = f2bs(p[j]);
        #pragma unroll
        for (int j = 4; j < 8; j++) v[j] = 0;
      } else {
        #pragma unroll
        for (int j = 0; j < 8; j++) v[j] = 0;
      }
      bi[s] = v;
    }
    const float binit = init_b[m];
    #pragma unroll
    for (int t = 0; t < 3; t++) {
      int R = t * 32;
      int u = R + m; if (u > 76) u = 76;
      float16 acc;
      #pragma unroll
      for (int r = 0; r < 16; r++) acc[r] = binit;
      #pragma unroll
      for (int s = 0; s < 7; s++) {
        short8 a = *(const short8*)&pool[u * 112 + s * 16 + kh * 8];
        acc = MFMA_B16(a, bi[s], acc);
      }
      #pragma unroll
      for (int r = 0; r < 16; r++) {
        int row = (r & 3) + 8 * (r >> 2) + 4 * kh;
        int uu = R + row;
        if (uu < W0) xbuf[uu * 32 + m] = f2bs(acc[r]);
      }
    }
  }
  __syncthreads();

  // ---- 16 layers, 2 barriers each; tiles parallel across waves ----
  int Win = W0;
  for (int i = 0; i < LL; i++) {
    const int d = 1 << (i & 3);
    const int Wout = Win - d - 1;
    const int T = (Wout + 32) >> 5;        // tile count, both phases
    const short* bw = bfw[i & 1];
    const float* bs = bias2[i & 1];

    // prefetch layer i+1 chunks into regs (commit at layer bottom)
    float pf[4][8];
    float pbias = 0.f;
    const int nch = (tid < 128) ? 4 : 3;   // 896 = 3*256 + 128
    if (i + 1 < LL) {
      #pragma unroll
      for (int q = 0; q < 4; q++) {
        if (q < nch)
          load_chunk(i + 1, tid + q * NT, pf[q], dil_w, filt_w, gate_w, res_w);
      }
      if (tid < 128) {
        const float* bsrc = (tid < 32) ? dil_b : (tid < 64) ? filt_b : (tid < 96) ? gate_b : res_b;
        pbias = bsrc[(i + 1) * 32 + (tid & 31)];
      }
    }

    // phase1: residual[vr] = db + D0@x[vr+d] + D1@x[vr], rows [0,Wout]
    float16 acc;                           // phase1 result stays live (f32 carry)
    if (wv < T) {
      const int R = wv * 32;
      short8 B0[2], B1[2];
      #pragma unroll
      for (int h = 0; h < 2; h++) {
        B0[h] = *(const short8*)&bw[((0 * 2 + h) * 64 + lane) * 8];
        B1[h] = *(const short8*)&bw[((1 * 2 + h) * 64 + lane) * 8];
      }
      int vra = R + m + d; if (vra > Win - 1) vra = Win - 1;
      int vrz = R + m;     if (vrz > Win - 1) vrz = Win - 1;
      short8 aA[2], aZ[2];
      afrag2(xbuf, vra, kh, aA);
      afrag2(xbuf, vrz, kh, aZ);
      const float bc = bs[m];
      #pragma unroll
      for (int r = 0; r < 16; r++) acc[r] = bc;
      acc = MFMA_B16(aA[0], B0[0], acc);
      acc = MFMA_B16(aA[1], B0[1], acc);
      acc = MFMA_B16(aZ[0], B1[0], acc);
      acc = MFMA_B16(aZ[1], B1[1], acc);
      #pragma unroll
      for (int r = 0; r < 16; r++) {
        int row = (r & 3) + 8 * (r >> 2) + 4 * kh;
        int vr = R + row;
        if (vr <= Wout) rb[vr * 32 + m] = f2bs(acc[r]);
      }
    }
    __syncthreads();

    // phase2+3 (same wave & tile; wave-local xm handoff via lgkmcnt)
    if (wv < T) {
      const int R = wv * 32;
      short8 BW[5][2];
      #pragma unroll
      for (int mt = 0; mt < 5; mt++)
        #pragma unroll
        for (int h = 0; h < 2; h++)
          BW[mt][h] = *(const short8*)&bw[(((mt + 2) * 2 + h) * 64 + lane) * 8];
      int r1 = R + m + 1; if (r1 > Wout) r1 = Wout;
      int r0 = R + m;     if (r0 > Wout) r0 = Wout;
      short8 a1[2], a0[2];
      afrag2(rb, r1, kh, a1);
      afrag2(rb, r0, kh, a0);
      float16 accF, accG;
      const float bf = bs[32 + m], bg = bs[64 + m];
      #pragma unroll
      for (int r = 0; r < 16; r++) { accF[r] = bf; accG[r] = bg; }
      accF = MFMA_B16(a1[0], BW[0][0], accF);
      accF = MFMA_B16(a1[1], BW[0][1], accF);
      accF = MFMA_B16(a0[0], BW[1][0], accF);
      accF = MFMA_B16(a0[1], BW[1][1], accF);
      accG = MFMA_B16(a1[0], BW[2][0], accG);
      accG = MFMA_B16(a1[1], BW[2][1], accG);
      accG = MFMA_B16(a0[0], BW[3][0], accG);
      accG = MFMA_B16(a0[1], BW[3][1], accG);
      #pragma unroll
      for (int r = 0; r < 16; r++) {
        int row = (r & 3) + 8 * (r >> 2) + 4 * kh;
        int uf = R + row;
        if (uf < Wout)
          xm[uf * 32 + m] = f2bs(fast_tanh(accF[r]) * fast_sigmoid(accG[r]));
      }
      asm volatile("s_waitcnt lgkmcnt(0)" ::: "memory");

      // phase3: xnext = rbias + R@xmid + residual[row+1]
      // residual[row+1] from phase1's f32 acc registers:
      //  (r&3)<3            -> acc[r+1]       (same lane)
      //  (r&3)==3, kh==0    -> partner(kh=1) acc[4q]   via shfl_xor 32
      //  (r&3)==3, kh==1,q<3-> partner(kh=0) acc[4q+4] via shfl_xor 32
      //  (r&3)==3, kh==1,q=3-> row 32: cross-wave, read rb[R+32] (post-barrier)
      float part[4];
      #pragma unroll
      for (int q = 0; q < 4; q++) {
        float sendv = (kh == 0) ? ((q < 3) ? acc[4 * q + 4] : 0.f) : acc[4 * q];
        part[q] = __shfl_xor(sendv, 32, 64);
      }
      float bnd = 0.f;
      {
        int rrB = R + 32; if (rrB > Wout) rrB = Wout;
        bnd = b2f(rb[rrB * 32 + m]);       // only consumed when R+32 <= Wout
      }
      int rx = R + m; if (rx > Wout - 1) rx = Wout - 1;
      short8 aX[2];
      afrag2(xm, rx, kh, aX);
      float16 accX;
      const float br = bs[96 + m];
      #pragma unroll
      for (int r = 0; r < 16; r++) {
        float resid;
        if ((r & 3) < 3)       resid = acc[r + 1];
        else if (kh == 0)      resid = part[r >> 2];
        else if ((r >> 2) < 3) resid = part[r >> 2];
        else                   resid = bnd;
        accX[r] = br + resid;
      }
      accX = MFMA_B16(aX[0], BW[4][0], accX);
      accX = MFMA_B16(aX[1], BW[4][1], accX);
      #pragma unroll
      for (int r = 0; r < 16; r++) {
        int row = (r & 3) + 8 * (r >> 2) + 4 * kh;
        int uf = R + row;
        if (uf < Wout) xbuf[uf * 32 + m] = f2bs(accX[r]);
      }
    }

    // commit layer i+1 frags (flip buffer; conflict-free b128 writes)
    if (i + 1 < LL) {
      short* dst = bfw[(i + 1) & 1];
      #pragma unroll
      for (int q = 0; q < 4; q++) {
        if (q < nch) {
          short8 v;
          #pragma unroll
          for (int j = 0; j < 8; j++) v[j] = f2bs(pf[q][j]);
          *(short8*)&dst[(tid + q * NT) * 8] = v;
        }
      }
      if (tid < 128) bias2[(i + 1) & 1][tid] = pbias;
    }
    __syncthreads();
    Win = Wout;
  }

  // ---- tail (f32 VALU, 4 waves): skip(l15) -> end1 -> end2 -> fc1..fc4 ----
  {
    float acc = skip_b[15 * 256 + tid];
    const float* wr = skip_w + (15 * 256 + tid) * 32;
    #pragma unroll
    for (int k = 0; k < 32; k += 4) {
      float4 w = *(const float4*)&wr[k];
      acc += (w.x * b2f(xm[k]) + w.y * b2f(xm[k+1])) + (w.z * b2f(xm[k+2]) + w.w * b2f(xm[k+3]));
    }
    vecA[tid] = fmaxf(acc, 0.f);
  }
  __syncthreads();
  {
    const float* wr = end1_w + tid * 256;
    float a4[4] = {0.f, 0.f, 0.f, 0.f};
    #pragma unroll 4
    for (int k = 0; k < 256; k += 16) {
      #pragma unroll
      for (int q = 0; q < 4; q++) {
        float4 w = *(const float4*)&wr[k + 4 * q];
        a4[q] += (w.x * vecA[k+4*q] + w.y * vecA[k+4*q+1]) + (w.z * vecA[k+4*q+2] + w.w * vecA[k+4*q+3]);
      }
    }
    vecB[tid] = fmaxf(end1_b[tid] + (a4[0] + a4[1]) + (a4[2] + a4[3]), 0.f);
  }
  __syncthreads();
  float h2;
  {
    const float* wr = end2_w + tid * 256;
    float a4[4] = {0.f, 0.f, 0.f, 0.f};
    #pragma unroll 4
    for (int k = 0; k < 256; k += 16) {
      #pragma unroll
      for (int q = 0; q < 4; q++) {
        float4 w = *(const float4*)&wr[k + 4 * q];
        a4[q] += (w.x * vecB[k+4*q] + w.y * vecB[k+4*q+1]) + (w.z * vecB[k+4*q+2] + w.w * vecB[k+4*q+3]);
      }
    }
    h2 = end2_b[tid] + (a4[0] + a4[1]) + (a4[2] + a4[3]);
  }
  __syncthreads();
  vecA[tid] = h2;
  __syncthreads();
  if (tid < 128) {
    const float* wr = fc1_w + tid * 256;
    float a4[4] = {0.f, 0.f, 0.f, 0.f};
    #pragma unroll 4
    for (int k = 0; k < 256; k += 16) {
      #pragma unroll
      for (int q = 0; q < 4; q++) {
        float4 w = *(const float4*)&wr[k + 4 * q];
        a4[q] += (w.x * vecA[k+4*q] + w.y * vecA[k+4*q+1]) + (w.z * vecA[k+4*q+2] + w.w * vecA[k+4*q+3]);
      }
    }
    vecB[tid] = fmaxf(fc1_b[tid] + (a4[0] + a4[1]) + (a4[2] + a4[3]), 0.f);
  }
  __syncthreads();
  if (tid < 128) {
    const float* wr = fc2_w + tid * 128;
    float a4[4] = {0.f, 0.f, 0.f, 0.f};
    #pragma unroll 2
    for (int k = 0; k < 128; k += 16) {
      #pragma unroll
      for (int q = 0; q < 4; q++) {
        float4 w = *(const float4*)&wr[k + 4 * q];
        a4[q] += (w.x * vecB[k+4*q] + w.y * vecB[k+4*q+1]) + (w.z * vecB[k+4*q+2] + w.w * vecB[k+4*q+3]);
      }
    }
    vecA[tid] = fmaxf(fc2_b[tid] + (a4[0] + a4[1]) + (a4[2] + a4[3]), 0.f);
  }
  __syncthreads();
  if (tid < 64) {
    const float* wr = fc3_w + tid * 128;
    float a4[4] = {0.f, 0.f, 0.f, 0.f};
    #pragma unroll 2
    for (int k = 0; k < 128; k += 16) {
      #pragma unroll
      for (int q = 0; q < 4; q++) {
        float4 w = *(const float4*)&wr[k + 4 * q];
        a4[q] += (w.x * vecA[k+4*q] + w.y * vecA[k+4*q+1]) + (w.z * vecA[k+4*q+2] + w.w * vecA[k+4*q+3]);
      }
    }
    vecB[tid] = fmaxf(fc3_b[tid] + (a4[0] + a4[1]) + (a4[2] + a4[3]), 0.f);
  }
  __syncthreads();
  {
    const float* wr = fc4_w + tid * 64;
    float a4[4] = {0.f, 0.f, 0.f, 0.f};
    #pragma unroll
    for (int k = 0; k < 64; k += 16) {
      #pragma unroll
      for (int q = 0; q < 4; q++) {
        float4 w = *(const float4*)&wr[k + 4 * q];
        a4[q] += (w.x * vecB[k+4*q] + w.y * vecB[k+4*q+1]) + (w.z * vecB[k+4*q+2] + w.w * vecB[k+4*q+3]);
      }
    }
    out[b * 256 + tid] = fc4_b[tid] + (a4[0] + a4[1]) + (a4[2] + a4[3]);
  }
}

extern "C" void kernel_launch(void* const* d_in, const int* in_sizes, int n_in,
                              void* d_out, int out_size, void* d_ws, size_t ws_size,
                              hipStream_t stream) {
  wavenet_kernel<<<BB, NT, 0, stream>>>(
      (const int*)d_in[0],    (const float*)d_in[1],  (const float*)d_in[2],  (const float*)d_in[3],
      (const float*)d_in[4],  (const float*)d_in[5],  (const float*)d_in[6],  (const float*)d_in[7],
      (const float*)d_in[8],  (const float*)d_in[9],  (const float*)d_in[10], (const float*)d_in[11],
      (const float*)d_in[12], (const float*)d_in[13], (const float*)d_in[14], (const float*)d_in[15],
      (const float*)d_in[16], (const float*)d_in[17], (const float*)d_in[18], (const float*)d_in[19],
      (const float*)d_in[20], (const float*)d_in[21], (const float*)d_in[22], (const float*)d_in[23],
      (const float*)d_in[24], (const float*)d_in[25], (float*)d_out);
}

// Round 13
// 209.625 us; speedup vs baseline: 1.0346x; 1.0346x over previous
//
#include <hip/hip_runtime.h>

// WaveNet inference on MFMA. Exploits: (1) only last timestep feeds the FC
// head, (2) skip overwritten each layer (only layer 15's matters),
// (3) receptive field at t=T-1 is 77 steps.
// Round 13 = exact R10 revert (best, 112us) + ONE shadowing tweak: the 10
// phase2/3 B-fragment ds_read_b128s are hoisted above the mid barrier into
// phase1's MFMA shadow (weight buffer is stable from layer top). Post-
// barrier chain now starts directly with the cross-wave activation reads.
// Regime rules learned (R3/4: >256 thr spills; R8: never trade CUs for
// waves; R9/R11: no serial work to kill barriers; R12: reg plumbing ~ LDS).

#define BB 16
#define TT 8192
#define LL 16
#define W0 77
#define NT 256

typedef __attribute__((ext_vector_type(8)))  short short8;
typedef __attribute__((ext_vector_type(16))) float float16;

#define MFMA_B16(a, b, c) __builtin_amdgcn_mfma_f32_32x32x16_bf16(a, b, c, 0, 0, 0)

__device__ __forceinline__ short f2bs(float f) {   // f32 -> bf16 bits, RNE
  union { float ff; unsigned u; } v; v.ff = f;
  unsigned u = v.u;
  return (short)((u + 0x7FFFu + ((u >> 16) & 1u)) >> 16);
}
__device__ __forceinline__ float b2f(short h) {
  union { unsigned u; float f; } v;
  v.u = ((unsigned)(unsigned short)h) << 16; return v.f;
}
__device__ __forceinline__ float fast_sigmoid(float x) {
  return 1.f / (1.f + __expf(-x));
}
__device__ __forceinline__ float fast_tanh(float x) {
  return 2.f / (1.f + __expf(-2.f * x)) - 1.f;
}

// A-fragment halves from [row][32] bf16 LDS: A[m][k], k-local=(lane>>5)*8+j.
__device__ __forceinline__ void afrag2(const short* src, int row, int kh, short8* out) {
  out[0] = *(const short8*)&src[row * 32 + 8 * kh];
  out[1] = *(const short8*)&src[row * 32 + 16 + 8 * kh];
}

// chunk cid in [0,896): mat=cid>>7, h=(cid>>6)&1, ln=cid&63 -> n=ln&31,k2=ln>>5
// value j: W[16h+8k2+j][n] of matrix mat; dst offset = cid*8 shorts (b128).
__device__ __forceinline__ void load_chunk(
    int li, int cid, float* pf,
    const float* dil_w, const float* filt_w, const float* gate_w, const float* res_w)
{
  int mat = cid >> 7;
  int h = (cid >> 6) & 1, ln = cid & 63;
  int n = ln & 31, k2 = ln >> 5;
  int base = (li * 32 + n) * 32 + 16 * h + 8 * k2;
  if (mat == 6) {
    const float* p = res_w + base;
    #pragma unroll
    for (int j = 0; j < 8; j++) pf[j] = p[j];
  } else {
    const float* w = (mat < 2) ? dil_w : (mat < 4) ? filt_w : gate_w;
    const float* p = w + base * 2 + (mat & 1);
    #pragma unroll
    for (int j = 0; j < 8; j++) pf[j] = p[2 * j];
  }
}

__global__ __launch_bounds__(NT, 1) void wavenet_kernel(
    const int* __restrict__ tokens,
    const float* __restrict__ emb,
    const float* __restrict__ init_w, const float* __restrict__ init_b,
    const float* __restrict__ dil_w,  const float* __restrict__ dil_b,
    const float* __restrict__ filt_w, const float* __restrict__ filt_b,
    const float* __restrict__ gate_w, const float* __restrict__ gate_b,
    const float* __restrict__ res_w,  const float* __restrict__ res_b,
    const float* __restrict__ skip_w, const float* __restrict__ skip_b,
    const float* __restrict__ end1_w, const float* __restrict__ end1_b,
    const float* __restrict__ end2_w, const float* __restrict__ end2_b,
    const float* __restrict__ fc1_w,  const float* __restrict__ fc1_b,
    const float* __restrict__ fc2_w,  const float* __restrict__ fc2_b,
    const float* __restrict__ fc3_w,  const float* __restrict__ fc3_b,
    const float* __restrict__ fc4_w,  const float* __restrict__ fc4_b,
    float* __restrict__ out)
{
  __shared__ __align__(16) short bfw[2][7168];   // weight frags, double buffer
  __shared__ float bias2[2][128];
  __shared__ __align__(16) short xbuf[W0 * 32];
  __shared__ __align__(16) short pool[8624];     // emb stage (init) / rb+xm
  __shared__ int tok[W0];
  __shared__ float vecA[256], vecB[256];

  short* rb = pool;          // 76*32
  short* xm = pool + 2432;   // 76*32

  const int tid  = threadIdx.x;
  const int lane = tid & 63;
  const int wv   = tid >> 6;
  const int m    = lane & 31;
  const int kh   = lane >> 5;
  const int b    = blockIdx.x;

  // ---- tokens ----
  if (tid < W0) tok[tid] = tokens[b * TT + (TT - 1 - tid)];
  __syncthreads();

  // ---- stage emb rows (bf16, rows zero-padded to K=112) ----
  for (int cid = tid; cid < 77 * 14; cid += NT) {
    int u = cid / 14, s = cid % 14;
    const float* er = emb + tok[u] * 100 + s * 8;
    short8 v;
    if (s < 12) {
      #pragma unroll
      for (int j = 0; j < 8; j++) v[j] = f2bs(er[j]);
    } else if (s == 12) {
      #pragma unroll
      for (int j = 0; j < 4; j++) v[j] = f2bs(er[j]);
      #pragma unroll
      for (int j = 4; j < 8; j++) v[j] = 0;
    } else {
      #pragma unroll
      for (int j = 0; j < 8; j++) v[j] = 0;
    }
    *(short8*)&pool[u * 112 + s * 8] = v;
  }
  // stage layer-0 weight frags + biases directly (all threads)
  for (int cid = tid; cid < 896; cid += NT) {
    float pf[8];
    load_chunk(0, cid, pf, dil_w, filt_w, gate_w, res_w);
    short8 v;
    #pragma unroll
    for (int j = 0; j < 8; j++) v[j] = f2bs(pf[j]);
    *(short8*)&bfw[0][cid * 8] = v;
  }
  if (tid < 128) {
    const float* bsrc = (tid < 32) ? dil_b : (tid < 64) ? filt_b : (tid < 96) ? gate_b : res_b;
    bias2[0][tid] = bsrc[tid & 31];
  }
  __syncthreads();

  // ---- init conv (wave 0, MFMA over K=112) ----
  if (wv == 0) {
    short8 bi[7];
    #pragma unroll
    for (int s = 0; s < 7; s++) {
      const float* p = init_w + m * 100 + s * 16 + kh * 8;
      short8 v;
      if (s < 6) {
        #pragma unroll
        for (int j = 0; j < 8; j++) v[j] = f2bs(p[j]);
      } else if (kh == 0) {
        #pragma unroll
        for (int j = 0; j < 4; j++) v[j] = f2bs(p[j]);
        #pragma unroll
        for (int j = 4; j < 8; j++) v[j] = 0;
      } else {
        #pragma unroll
        for (int j = 0; j < 8; j++) v[j] = 0;
      }
      bi[s] = v;
    }
    const float binit = init_b[m];
    #pragma unroll
    for (int t = 0; t < 3; t++) {
      int R = t * 32;
      int u = R + m; if (u > 76) u = 76;
      float16 acc;
      #pragma unroll
      for (int r = 0; r < 16; r++) acc[r] = binit;
      #pragma unroll
      for (int s = 0; s < 7; s++) {
        short8 a = *(const short8*)&pool[u * 112 + s * 16 + kh * 8];
        acc = MFMA_B16(a, bi[s], acc);
      }
      #pragma unroll
      for (int r = 0; r < 16; r++) {
        int row = (r & 3) + 8 * (r >> 2) + 4 * kh;
        int uu = R + row;
        if (uu < W0) xbuf[uu * 32 + m] = f2bs(acc[r]);
      }
    }
  }
  __syncthreads();

  // ---- 16 layers, 2 barriers each; tiles parallel across waves ----
  int Win = W0;
  for (int i = 0; i < LL; i++) {
    const int d = 1 << (i & 3);
    const int Wout = Win - d - 1;
    const int T = (Wout + 32) >> 5;        // tile count, both phases
    const short* bw = bfw[i & 1];
    const float* bs = bias2[i & 1];

    // prefetch layer i+1 chunks into regs (commit at layer bottom)
    float pf[4][8];
    float pbias = 0.f;
    const int nch = (tid < 128) ? 4 : 3;   // 896 = 3*256 + 128
    if (i + 1 < LL) {
      #pragma unroll
      for (int q = 0; q < 4; q++) {
        if (q < nch)
          load_chunk(i + 1, tid + q * NT, pf[q], dil_w, filt_w, gate_w, res_w);
      }
      if (tid < 128) {
        const float* bsrc = (tid < 32) ? dil_b : (tid < 64) ? filt_b : (tid < 96) ? gate_b : res_b;
        pbias = bsrc[(i + 1) * 32 + (tid & 31)];
      }
    }

    // phase1: residual[vr] = db + D0@x[vr+d] + D1@x[vr], rows [0,Wout]
    // + hoisted phase2/3 B-frag loads (weight buffer stable from layer top;
    //   latency hides under phase1's MFMA chain, lives across mid barrier)
    short8 BW[5][2];
    if (wv < T) {
      const int R = wv * 32;
      short8 B0[2], B1[2];
      #pragma unroll
      for (int h = 0; h < 2; h++) {
        B0[h] = *(const short8*)&bw[((0 * 2 + h) * 64 + lane) * 8];
        B1[h] = *(const short8*)&bw[((1 * 2 + h) * 64 + lane) * 8];
      }
      #pragma unroll
      for (int mt = 0; mt < 5; mt++)
        #pragma unroll
        for (int h = 0; h < 2; h++)
          BW[mt][h] = *(const short8*)&bw[(((mt + 2) * 2 + h) * 64 + lane) * 8];
      int vra = R + m + d; if (vra > Win - 1) vra = Win - 1;
      int vrz = R + m;     if (vrz > Win - 1) vrz = Win - 1;
      short8 aA[2], aZ[2];
      afrag2(xbuf, vra, kh, aA);
      afrag2(xbuf, vrz, kh, aZ);
      float16 acc;
      const float bc = bs[m];
      #pragma unroll
      for (int r = 0; r < 16; r++) acc[r] = bc;
      acc = MFMA_B16(aA[0], B0[0], acc);
      acc = MFMA_B16(aA[1], B0[1], acc);
      acc = MFMA_B16(aZ[0], B1[0], acc);
      acc = MFMA_B16(aZ[1], B1[1], acc);
      #pragma unroll
      for (int r = 0; r < 16; r++) {
        int row = (r & 3) + 8 * (r >> 2) + 4 * kh;
        int vr = R + row;
        if (vr <= Wout) rb[vr * 32 + m] = f2bs(acc[r]);
      }
    }
    __syncthreads();

    // phase2+3 (same wave & tile; wave-local xm handoff via lgkmcnt)
    if (wv < T) {
      const int R = wv * 32;
      int r1 = R + m + 1; if (r1 > Wout) r1 = Wout;
      int r0 = R + m;     if (r0 > Wout) r0 = Wout;
      short8 a1[2], a0[2];
      afrag2(rb, r1, kh, a1);
      afrag2(rb, r0, kh, a0);
      float16 accF, accG;
      const float bf = bs[32 + m], bg = bs[64 + m];
      #pragma unroll
      for (int r = 0; r < 16; r++) { accF[r] = bf; accG[r] = bg; }
      accF = MFMA_B16(a1[0], BW[0][0], accF);
      accF = MFMA_B16(a1[1], BW[0][1], accF);
      accF = MFMA_B16(a0[0], BW[1][0], accF);
      accF = MFMA_B16(a0[1], BW[1][1], accF);
      accG = MFMA_B16(a1[0], BW[2][0], accG);
      accG = MFMA_B16(a1[1], BW[2][1], accG);
      accG = MFMA_B16(a0[0], BW[3][0], accG);
      accG = MFMA_B16(a0[1], BW[3][1], accG);
      #pragma unroll
      for (int r = 0; r < 16; r++) {
        int row = (r & 3) + 8 * (r >> 2) + 4 * kh;
        int uf = R + row;
        if (uf < Wout)
          xm[uf * 32 + m] = f2bs(fast_tanh(accF[r]) * fast_sigmoid(accG[r]));
      }
      asm volatile("s_waitcnt lgkmcnt(0)" ::: "memory");

      // phase3: xnext = rbias + R@xmid + residual[row+1] (bf16 carry in C)
      int rx = R + m; if (rx > Wout - 1) rx = Wout - 1;
      short8 aX[2];
      afrag2(xm, rx, kh, aX);
      float16 accX;
      const float br = bs[96 + m];
      #pragma unroll
      for (int r = 0; r < 16; r++) {
        int row = (r & 3) + 8 * (r >> 2) + 4 * kh;
        int rr = R + row + 1; if (rr > Wout) rr = Wout;
        accX[r] = br + b2f(rb[rr * 32 + m]);
      }
      accX = MFMA_B16(aX[0], BW[4][0], accX);
      accX = MFMA_B16(aX[1], BW[4][1], accX);
      #pragma unroll
      for (int r = 0; r < 16; r++) {
        int row = (r & 3) + 8 * (r >> 2) + 4 * kh;
        int uf = R + row;
        if (uf < Wout) xbuf[uf * 32 + m] = f2bs(accX[r]);
      }
    }

    // commit layer i+1 frags (flip buffer; conflict-free b128 writes)
    if (i + 1 < LL) {
      short* dst = bfw[(i + 1) & 1];
      #pragma unroll
      for (int q = 0; q < 4; q++) {
        if (q < nch) {
          short8 v;
          #pragma unroll
          for (int j = 0; j < 8; j++) v[j] = f2bs(pf[q][j]);
          *(short8*)&dst[(tid + q * NT) * 8] = v;
        }
      }
      if (tid < 128) bias2[(i + 1) & 1][tid] = pbias;
    }
    __syncthreads();
    Win = Wout;
  }

  // ---- tail (f32 VALU, 4 waves): skip(l15) -> end1 -> end2 -> fc1..fc4 ----
  {
    float acc = skip_b[15 * 256 + tid];
    const float* wr = skip_w + (15 * 256 + tid) * 32;
    #pragma unroll
    for (int k = 0; k < 32; k += 4) {
      float4 w = *(const float4*)&wr[k];
      acc += (w.x * b2f(xm[k]) + w.y * b2f(xm[k+1])) + (w.z * b2f(xm[k+2]) + w.w * b2f(xm[k+3]));
    }
    vecA[tid] = fmaxf(acc, 0.f);
  }
  __syncthreads();
  {
    const float* wr = end1_w + tid * 256;
    float a4[4] = {0.f, 0.f, 0.f, 0.f};
    #pragma unroll 4
    for (int k = 0; k < 256; k += 16) {
      #pragma unroll
      for (int q = 0; q < 4; q++) {
        float4 w = *(const float4*)&wr[k + 4 * q];
        a4[q] += (w.x * vecA[k+4*q] + w.y * vecA[k+4*q+1]) + (w.z * vecA[k+4*q+2] + w.w * vecA[k+4*q+3]);
      }
    }
    vecB[tid] = fmaxf(end1_b[tid] + (a4[0] + a4[1]) + (a4[2] + a4[3]), 0.f);
  }
  __syncthreads();
  float h2;
  {
    const float* wr = end2_w + tid * 256;
    float a4[4] = {0.f, 0.f, 0.f, 0.f};
    #pragma unroll 4
    for (int k = 0; k < 256; k += 16) {
      #pragma unroll
      for (int q = 0; q < 4; q++) {
        float4 w = *(const float4*)&wr[k + 4 * q];
        a4[q] += (w.x * vecB[k+4*q] + w.y * vecB[k+4*q+1]) + (w.z * vecB[k+4*q+2] + w.w * vecB[k+4*q+3]);
      }
    }
    h2 = end2_b[tid] + (a4[0] + a4[1]) + (a4[2] + a4[3]);
  }
  __syncthreads();
  vecA[tid] = h2;
  __syncthreads();
  if (tid < 128) {
    const float* wr = fc1_w + tid * 256;
    float a4[4] = {0.f, 0.f, 0.f, 0.f};
    #pragma unroll 4
    for (int k = 0; k < 256; k += 16) {
      #pragma unroll
      for (int q = 0; q < 4; q++) {
        float4 w = *(const float4*)&wr[k + 4 * q];
        a4[q] += (w.x * vecA[k+4*q] + w.y * vecA[k+4*q+1]) + (w.z * vecA[k+4*q+2] + w.w * vecA[k+4*q+3]);
      }
    }
    vecB[tid] = fmaxf(fc1_b[tid] + (a4[0] + a4[1]) + (a4[2] + a4[3]), 0.f);
  }
  __syncthreads();
  if (tid < 128) {
    const float* wr = fc2_w + tid * 128;
    float a4[4] = {0.f, 0.f, 0.f, 0.f};
    #pragma unroll 2
    for (int k = 0; k < 128; k += 16) {
      #pragma unroll
      for (int q = 0; q < 4; q++) {
        float4 w = *(const float4*)&wr[k + 4 * q];
        a4[q] += (w.x * vecB[k+4*q] + w.y * vecB[k+4*q+1]) + (w.z * vecB[k+4*q+2] + w.w * vecB[k+4*q+3]);
      }
    }
    vecA[tid] = fmaxf(fc2_b[tid] + (a4[0] + a4[1]) + (a4[2] + a4[3]), 0.f);
  }
  __syncthreads();
  if (tid < 64) {
    const float* wr = fc3_w + tid * 128;
    float a4[4] = {0.f, 0.f, 0.f, 0.f};
    #pragma unroll 2
    for (int k = 0; k < 128; k += 16) {
      #pragma unroll
      for (int q = 0; q < 4; q++) {
        float4 w = *(const float4*)&wr[k + 4 * q];
        a4[q] += (w.x * vecA[k+4*q] + w.y * vecA[k+4*q+1]) + (w.z * vecA[k+4*q+2] + w.w * vecA[k+4*q+3]);
      }
    }
    vecB[tid] = fmaxf(fc3_b[tid] + (a4[0] + a4[1]) + (a4[2] + a4[3]), 0.f);
  }
  __syncthreads();
  {
    const float* wr = fc4_w + tid * 64;
    float a4[4] = {0.f, 0.f, 0.f, 0.f};
    #pragma unroll
    for (int k = 0; k < 64; k += 16) {
      #pragma unroll
      for (int q = 0; q < 4; q++) {
        float4 w = *(const float4*)&wr[k + 4 * q];
        a4[q] += (w.x * vecB[k+4*q] + w.y * vecB[k+4*q+1]) + (w.z * vecB[k+4*q+2] + w.w * vecB[k+4*q+3]);
      }
    }
    out[b * 256 + tid] = fc4_b[tid] + (a4[0] + a4[1]) + (a4[2] + a4[3]);
  }
}

extern "C" void kernel_launch(void* const* d_in, const int* in_sizes, int n_in,
                              void* d_out, int out_size, void* d_ws, size_t ws_size,
                              hipStream_t stream) {
  wavenet_kernel<<<BB, NT, 0, stream>>>(
      (const int*)d_in[0],    (const float*)d_in[1],  (const float*)d_in[2],  (const float*)d_in[3],
      (const float*)d_in[4],  (const float*)d_in[5],  (const float*)d_in[6],  (const float*)d_in[7],
      (const float*)d_in[8],  (const float*)d_in[9],  (const float*)d_in[10], (const float*)d_in[11],
      (const float*)d_in[12], (const float*)d_in[13], (const float*)d_in[14], (const float*)d_in[15],
      (const float*)d_in[16], (const float*)d_in[17], (const float*)d_in[18], (const float*)d_in[19],
      (const float*)d_in[20], (const float*)d_in[21], (const float*)d_in[22], (const float*)d_in[23],
      (const float*)d_in[24], (const float*)d_in[25], (float*)d_out);
}